// Round 5
// baseline (296.253 us; speedup 1.0000x reference)
//
#include <hip/hip_runtime.h>

#define NH 16
#define SLEN 2048
#define DMODEL 1024
#define DHEAD 64
#define WIN 512
#define NB 4

typedef unsigned short u16;
typedef unsigned int u32;
typedef unsigned long long u64;
typedef __attribute__((ext_vector_type(8))) __bf16 bf16x8;
typedef __attribute__((ext_vector_type(4))) float floatx4;

__device__ __forceinline__ float b2f(u32 bits16) {
  union { u32 i; float f; } x; x.i = bits16 << 16; return x.f;
}
__device__ __forceinline__ u16 f2b(float f) {
  union { float f; u32 i; } x; x.f = f;
  u32 r = x.i + 0x7fffu + ((x.i >> 16) & 1u);
  return (u16)(r >> 16);
}

// async global->LDS, 16B/lane; LDS dest must be wave-uniform base + lane*16
__device__ __forceinline__ void gl2lds16(const u16* g, u16* l) {
  __builtin_amdgcn_global_load_lds(
      (const __attribute__((address_space(1))) unsigned int*)g,
      (__attribute__((address_space(3))) unsigned int*)l, 16, 0, 0);
}

// inline-asm LDS read: invisible to compiler alias analysis; completion is
// managed by explicit counted lgkmcnt + sched_barrier(0) (rule #18).
template<int OFF>
__device__ __forceinline__ bf16x8 ldsr128(u32 addr) {
  bf16x8 r;
  if constexpr (OFF == 0)
    asm volatile("ds_read_b128 %0, %1" : "=v"(r) : "v"(addr));
  else
    asm volatile("ds_read_b128 %0, %1 offset:%2" : "=v"(r) : "v"(addr), "i"(OFF));
  return r;
}

#define WAIT_VM8   asm volatile("s_waitcnt vmcnt(8)" ::: "memory")
#define WAIT_VM0   asm volatile("s_waitcnt vmcnt(0)" ::: "memory")
#define WAIT_LGKM0 asm volatile("s_waitcnt lgkmcnt(0)" ::: "memory")
#define SCHEDB     __builtin_amdgcn_sched_barrier(0)
#define SBAR       __builtin_amdgcn_s_barrier()

// ---------------- fused prep: cvt + weight packs + rotary table ----------------
__global__ __launch_bounds__(256) void prep_all(
    const float* __restrict__ tokens, const float* __restrict__ Wq,
    const float* __restrict__ Wkv, const float* __restrict__ Wout,
    const float* __restrict__ Wmix, const float* __restrict__ Wgate,
    u64* __restrict__ tokA64, u16* __restrict__ WqkvT, u16* __restrict__ WoutT,
    u16* __restrict__ Wmg, float2* __restrict__ rtab) {
  __shared__ u16 T[64][72];
  const int blk = blockIdx.x, tid = threadIdx.x;
  if (blk < 8192) {
    int i = blk * 256 + tid;
    float4 f = reinterpret_cast<const float4*>(tokens)[i];
    union { u16 u[4]; u64 ll; } pk;
    pk.u[0] = f2b(f.x); pk.u[1] = f2b(f.y); pk.u[2] = f2b(f.z); pk.u[3] = f2b(f.w);
    tokA64[i] = pk.ll;
  } else if (blk < 9216) {
    const float* src; u16* dst; int ld, nb, n0, k0;
    if (blk < 8960) {
      int tile = blk - 8192;                      // 48 n-tiles x 16 k-tiles
      n0 = (tile % 48) * 64; k0 = (tile / 48) * 64;
      if (n0 < 1024) { src = Wq; ld = 1024; nb = n0; }
      else { src = Wkv; ld = 2048; nb = n0 - 1024; }
      dst = WqkvT;
    } else {
      int tile = blk - 8960;                      // 16 x 16
      n0 = (tile % 16) * 64; k0 = (tile / 16) * 64;
      src = Wout; ld = 1024; nb = n0; dst = WoutT;
    }
#pragma unroll
    for (int i = 0; i < 16; ++i) {
      int e = i * 256 + tid;
      int kr = e >> 6, nc = e & 63;
      T[kr][nc] = f2b(src[(size_t)(k0 + kr) * ld + nb + nc]);
    }
    __syncthreads();
#pragma unroll
    for (int i = 0; i < 16; ++i) {
      int e = i * 256 + tid;
      int nr = e >> 6, kc = e & 63;
      dst[(size_t)(n0 + nr) * 1024 + k0 + kc] = T[kc][nr];
    }
  } else if (blk < 9344) {
    int idx = (blk - 9216) * 256 + tid;           // 32768
    int n = idx >> 10, k = idx & 1023;
    float v = (n < 16) ? Wmix[k * 16 + n] : Wgate[k * 16 + (n - 16)];
    Wmg[idx] = f2b(v);
  } else {
    int idx = (blk - 9344) * 256 + tid;           // 65536
    int s = idx >> 5, t = idx & 31;
    float inv = __expf((float)t * -0.2878231366f);
    float ang = (float)s * inv;
    float sn, cs;
    __sincosf(ang, &sn, &cs);
    rtab[idx] = make_float2(cs, sn);
  }
}

// ---------------- mix / gate via MFMA ----------------
__global__ __launch_bounds__(256) void mixgate_mfma(const u16* __restrict__ A,
    const u16* __restrict__ Wmg, float* __restrict__ mixws, float* __restrict__ gatews) {
  const int lane = threadIdx.x & 63, w = threadIdx.x >> 6;
  const int lm = lane & 15, quad = lane >> 4;
  const int row0 = (blockIdx.x * 4 + w) * 32;

  floatx4 acc[2][2];
#pragma unroll
  for (int i = 0; i < 2; ++i)
#pragma unroll
    for (int j = 0; j < 2; ++j)
      acc[i][j] = (floatx4){0.f, 0.f, 0.f, 0.f};

#pragma unroll 4
  for (int k0 = 0; k0 < 1024; k0 += 32) {
    bf16x8 af[2], bf[2];
#pragma unroll
    for (int mt = 0; mt < 2; ++mt)
      af[mt] = *reinterpret_cast<const bf16x8*>(
          &A[(size_t)(row0 + mt * 16 + lm) * 1024 + k0 + quad * 8]);
#pragma unroll
    for (int nt = 0; nt < 2; ++nt)
      bf[nt] = *reinterpret_cast<const bf16x8*>(
          &Wmg[(size_t)(nt * 16 + lm) * 1024 + k0 + quad * 8]);
#pragma unroll
    for (int mt = 0; mt < 2; ++mt)
#pragma unroll
      for (int nt = 0; nt < 2; ++nt)
        acc[mt][nt] = __builtin_amdgcn_mfma_f32_16x16x32_bf16(af[mt], bf[nt], acc[mt][nt], 0, 0, 0);
  }

#pragma unroll
  for (int mt = 0; mt < 2; ++mt)
#pragma unroll
    for (int r = 0; r < 4; ++r) {
      int grow = row0 + mt * 16 + quad * 4 + r;
      int b = grow >> 11, s = grow & 2047;
#pragma unroll
      for (int nt = 0; nt < 2; ++nt) {
        int n = nt * 16 + lm;
        float sig = 1.0f / (1.0f + __expf(-acc[mt][nt][r]));
        int h = n & 15;
        (n < 16 ? mixws : gatews)[(b * NH + h) * SLEN + s] = sig;
      }
    }
}

// ---------------- 256x256 8-phase MFMA GEMM (m201 template port) ----------------
// BM=BN=256, BK=64. 8 waves 2M x 4N (128x64 per wave). 2 LDS K-tile buffers
// (64KB each = A 256x64 + B 256x64). Per K-tile, 4 phases, each computing one
// C-quadrant (4mt x 2nt x 2kk = 16 MFMA):
//   P1 (qm0,qn0): read A-qm0 (8 ds) + B-qn0 (4 ds)
//   P2 (qm0,qn1): read B-qn1 (4 ds)          [B frags register-cached all tile]
//   P3 (qm1,qn0): read A-qm1 (8 ds) + STAGE B-halves of tile t+2 (4 gl2lds)
//   P4 (qm1,qn1): STAGE A-halves of tile t+2 (4 gl2lds)
// Each phase: {reads/stage; SBAR; lgkmcnt(0); setprio(1); 16 MFMA; setprio(0); SBAR}.
// Tile-top: vmcnt(8) (tile t's 8 loads oldest; t+1's 8 stay in flight) + SBAR.
// Region hazards: B regions last read P2 -> staged P3; A regions last read P3 ->
// staged P4; every stage issue is after an end-of-phase barrier that follows all
// waves' lgkmcnt(0). Swizzle: chunk (row,c)[16B] at slot c^(row&7), via
// inverse-swizzled global source + linear LDS dest (gl2lds constraint).
template<int MODE>
__global__ __launch_bounds__(512, 2) void gemm_pipe(
    const u16* __restrict__ A, const u16* __restrict__ Bt,
    float* __restrict__ C,
    u16* __restrict__ qws, u16* __restrict__ kws, u16* __restrict__ vws,
    const float* __restrict__ vres, const float* __restrict__ mixws,
    const float2* __restrict__ rtab, int N) {
  __shared__ u16 smem[65536];                     // 128KB: 2 x (A 32KB + B 32KB)
  const int tid = threadIdx.x;
  const int nbx = N >> 8;
  const int wg = (blockIdx.x & 7) * (gridDim.x >> 3) + (blockIdx.x >> 3);
  const int bx = wg % nbx, by = wg / nbx;
  const int row0 = by * 256, col0 = bx * 256;
  const int w = tid >> 6, lane = tid & 63;
  const int wm = w >> 2, wn = w & 3;              // 2M x 4N; wave tile 128x64
  const int lm = lane & 15, quad = lane >> 4;
  const int NT = 16;                              // K = 1024, BK = 64

  // staging: per (h,g) unit of 64 rows, thread covers row tid>>3, slot tid&7
  const int sr = tid >> 3, sc = tid & 7;
  const u16* gA0 = A + (size_t)(row0 + sr) * 1024 + ((sc ^ (sr & 7)) << 3);
  const u16* gB0 = Bt + (size_t)(col0 + sr) * 1024 + ((sc ^ (sr & 7)) << 3);

  const u32 ldsb = (u32)(size_t)(__attribute__((address_space(3))) u16*)smem;
  const u32 xorq = (u32)(quad ^ (lm & 7)) * 16;
  const u32 aR = (u32)(wm * 128 + lm) * 128 + xorq;          // byte; +qm*8192
  const u32 bR = 32768u + (u32)(wn * 64 + lm) * 128 + xorq;  // byte; +qn*4096

  floatx4 acc[8][4];
#pragma unroll
  for (int i = 0; i < 8; ++i)
#pragma unroll
    for (int j = 0; j < 4; ++j)
      acc[i][j] = (floatx4){0.f, 0.f, 0.f, 0.f};

  auto stageA2 = [&](int buf, int t2, int h) {     // one A-half: 2 loads
    const u16* g = gA0 + (size_t)h * 131072 + t2 * 64;
    u16* d = smem + buf * 32768 + h * 8192 + (tid << 3);
    gl2lds16(g, d);
    gl2lds16(g + 65536, d + 4096);
  };
  auto stageB2 = [&](int buf, int t2, int h) {     // one B-half: 2 loads
    const u16* g = gB0 + (size_t)h * 131072 + t2 * 64;
    u16* d = smem + buf * 32768 + 16384 + h * 8192 + (tid << 3);
    gl2lds16(g, d);
    gl2lds16(g + 65536, d + 4096);
  };

  // prologue: tile0 -> buf0 (8 loads), tile1 -> buf1 (8 loads)
  stageA2(0, 0, 0); stageA2(0, 0, 1); stageB2(0, 0, 0); stageB2(0, 0, 1);
  stageA2(1, 1, 0); stageA2(1, 1, 1); stageB2(1, 1, 0); stageB2(1, 1, 1);

  for (int t = 0; t < NT; ++t) {
    const int cur = t & 1;
    const u32 base = ldsb + (u32)cur * 65536u;
    const bool ds = t < NT - 2;

    if (t < NT - 1) { WAIT_VM8; } else { WAIT_VM0; }
    SBAR;

    bf16x8 a0[4], a1[4], b00[2], b10[2], b01[2], b11[2];
    // ---- P1 (qm0,qn0): A-qm0 (8) + B-qn0 (4)
    {
      u32 aa = base + aR;
      a0[0] = ldsr128<0>(aa);    a0[1] = ldsr128<2048>(aa);
      a0[2] = ldsr128<4096>(aa); a0[3] = ldsr128<6144>(aa);
      u32 ab = aa ^ 64u;
      a1[0] = ldsr128<0>(ab);    a1[1] = ldsr128<2048>(ab);
      a1[2] = ldsr128<4096>(ab); a1[3] = ldsr128<6144>(ab);
      u32 ba = base + bR;
      b00[0] = ldsr128<0>(ba);   b00[1] = ldsr128<2048>(ba);
      u32 bb = ba ^ 64u;
      b10[0] = ldsr128<0>(bb);   b10[1] = ldsr128<2048>(bb);
    }
    SCHEDB; SBAR; WAIT_LGKM0; SCHEDB;
    __builtin_amdgcn_s_setprio(1);
#pragma unroll
    for (int i = 0; i < 4; ++i)
#pragma unroll
      for (int j = 0; j < 2; ++j) {
        acc[i][j] = __builtin_amdgcn_mfma_f32_16x16x32_bf16(a0[i], b00[j], acc[i][j], 0, 0, 0);
        acc[i][j] = __builtin_amdgcn_mfma_f32_16x16x32_bf16(a1[i], b10[j], acc[i][j], 0, 0, 0);
      }
    __builtin_amdgcn_s_setprio(0);
    SBAR;

    // ---- P2 (qm0,qn1): B-qn1 (4)
    {
      u32 ba = base + bR + 4096u;
      b01[0] = ldsr128<0>(ba);   b01[1] = ldsr128<2048>(ba);
      u32 bb = ba ^ 64u;
      b11[0] = ldsr128<0>(bb);   b11[1] = ldsr128<2048>(bb);
    }
    SCHEDB; SBAR; WAIT_LGKM0; SCHEDB;
    __builtin_amdgcn_s_setprio(1);
#pragma unroll
    for (int i = 0; i < 4; ++i)
#pragma unroll
      for (int j = 0; j < 2; ++j) {
        acc[i][2 + j] = __builtin_amdgcn_mfma_f32_16x16x32_bf16(a0[i], b01[j], acc[i][2 + j], 0, 0, 0);
        acc[i][2 + j] = __builtin_amdgcn_mfma_f32_16x16x32_bf16(a1[i], b11[j], acc[i][2 + j], 0, 0, 0);
      }
    __builtin_amdgcn_s_setprio(0);
    SBAR;

    // ---- P3 (qm1,qn0): A-qm1 (8) + stage B-halves of tile t+2
    {
      u32 aa = base + aR + 8192u;
      a0[0] = ldsr128<0>(aa);    a0[1] = ldsr128<2048>(aa);
      a0[2] = ldsr128<4096>(aa); a0[3] = ldsr128<6144>(aa);
      u32 ab = aa ^ 64u;
      a1[0] = ldsr128<0>(ab);    a1[1] = ldsr128<2048>(ab);
      a1[2] = ldsr128<4096>(ab); a1[3] = ldsr128<6144>(ab);
    }
    if (ds) { stageB2(cur, t + 2, 0); stageB2(cur, t + 2, 1); }
    SCHEDB; SBAR; WAIT_LGKM0; SCHEDB;
    __builtin_amdgcn_s_setprio(1);
#pragma unroll
    for (int i = 0; i < 4; ++i)
#pragma unroll
      for (int j = 0; j < 2; ++j) {
        acc[4 + i][j] = __builtin_amdgcn_mfma_f32_16x16x32_bf16(a0[i], b00[j], acc[4 + i][j], 0, 0, 0);
        acc[4 + i][j] = __builtin_amdgcn_mfma_f32_16x16x32_bf16(a1[i], b10[j], acc[4 + i][j], 0, 0, 0);
      }
    __builtin_amdgcn_s_setprio(0);
    SBAR;

    // ---- P4 (qm1,qn1): stage A-halves of tile t+2
    if (ds) { stageA2(cur, t + 2, 0); stageA2(cur, t + 2, 1); }
    SCHEDB; SBAR; SCHEDB;
    __builtin_amdgcn_s_setprio(1);
#pragma unroll
    for (int i = 0; i < 4; ++i)
#pragma unroll
      for (int j = 0; j < 2; ++j) {
        acc[4 + i][2 + j] = __builtin_amdgcn_mfma_f32_16x16x32_bf16(a0[i], b01[j], acc[4 + i][2 + j], 0, 0, 0);
        acc[4 + i][2 + j] = __builtin_amdgcn_mfma_f32_16x16x32_bf16(a1[i], b11[j], acc[4 + i][2 + j], 0, 0, 0);
      }
    __builtin_amdgcn_s_setprio(0);
    SBAR;
  }

  if (MODE == 0) {
#pragma unroll
    for (int mt = 0; mt < 8; ++mt)
#pragma unroll
      for (int r = 0; r < 4; ++r) {
        int grow = row0 + wm * 128 + mt * 16 + quad * 4 + r;
#pragma unroll
        for (int nt = 0; nt < 4; ++nt)
          C[(size_t)grow * N + col0 + wn * 64 + nt * 16 + lm] = acc[mt][nt][r];
      }
  } else {
    const int seg = col0 >> 10;                   // 0=q, 1=k, 2=v (uniform/block)
    if (seg < 2) {
      u16* dst = seg ? kws : qws;
      const float qs = seg ? 1.0f : 0.125f;       // D^-0.5 on q
      const int colb = (col0 & 1023) + wn * 64;   // wave covers exactly 1 head
#pragma unroll
      for (int mt = 0; mt < 8; ++mt)
#pragma unroll
        for (int r = 0; r < 4; ++r) {
          int sg = row0 + wm * 128 + mt * 16 + quad * 4 + r;
          int b = sg >> 11, s = sg & 2047;
#pragma unroll
          for (int nt = 0; nt < 4; ++nt) {
            int nn = colb + nt * 16 + lm;
            int h = nn >> 6, d = nn & 63;
            float val = acc[mt][nt][r] * qs;
            float2 cs = rtab[(s << 5) + (d >> 1)];
            float partner = __shfl_xor(val, 1);
            float o = (d & 1) ? fmaf(val, cs.x, partner * cs.y)
                              : fmaf(val, cs.x, -partner * cs.y);
            dst[((size_t)((b * NH + h) * SLEN + s)) * 64 + d] = f2b(o);
          }
        }
    } else {
      // v: blend with residual by mix, transpose to (b,h,d,s) via LDS.
      // Block covers 4 heads (256 cols); wave wn owns head h0+wn, wm halves rows.
      // Vt: 4 heads x [64 d][256 s] u16 = exactly 128KB (reuses main-loop smem).
      const int h0 = (col0 - 2048) >> 6;
      const int b = row0 >> 11, s0 = row0 & 2047;
      const int bh = b * NH + h0 + wn;
      u16* VtW = smem + wn * 16384;
      __syncthreads();                            // main-loop smem retired
#pragma unroll
      for (int mt = 0; mt < 8; ++mt)
#pragma unroll
        for (int nt = 0; nt < 4; ++nt) {
          const int d = nt * 16 + lm;
          const int sl = wm * 128 + mt * 16 + quad * 4;
          union { u16 u[4]; u64 ll; } pk;
#pragma unroll
          for (int r = 0; r < 4; ++r) {
            int s = s0 + sl + r;
            float val = acc[mt][nt][r];
            float mv = mixws[bh * SLEN + s];
            float o = val + (vres[((size_t)(bh * SLEN + s)) * 64 + d] - val) * mv;
            pk.u[r] = f2b(o);
          }
          *reinterpret_cast<u64*>(&VtW[d * 256 + sl]) = pk.ll;
        }
      __syncthreads();
      // copy out: 4 heads x 64 d x 32 chunks(16B) = 8192 chunks / 512 thr
#pragma unroll
      for (int it = 0; it < 16; ++it) {
        int idx = it * 512 + tid;
        int hd = idx >> 11, rem = idx & 2047;
        int d = rem >> 5, ch = rem & 31;
        const u16* src = smem + hd * 16384 + d * 256 + ch * 8;
        u16* dstp = vws + ((size_t)((b * NH + h0 + hd) * 64 + d)) * SLEN + s0 + ch * 8;
        *reinterpret_cast<uint4*>(dstp) = *reinterpret_cast<const uint4*>(src);
      }
    }
  }
}

// ---------------- MFMA flash attention: swizzled K/V LDS + double-buffer ----------
__global__ __launch_bounds__(256) void attn_mfma_kernel(
    const u16* __restrict__ q, const u16* __restrict__ k, const u16* __restrict__ vt,
    const float* __restrict__ gate, u16* __restrict__ X) {
  __shared__ __align__(16) u16 Ks[2][4096];   // [buf][j 64][8 swizzled 16B chunks]
  __shared__ __align__(16) u16 Vs[2][4096];   // [buf][d 64][8 swizzled 16B chunks]
  __shared__ __align__(16) u16 Ps[4][16][72]; // [wave][q-local][j 64 + pad]
  const int tid = threadIdx.x;
  const int w = tid >> 6, lane = tid & 63;
  const int lm = lane & 15, quad = lane >> 4;
  const int blk = blockIdx.x;            // b*512 + h*32 + qt
  const int qt = blk & 31;
  const int h = (blk >> 5) & 15;
  const int b = blk >> 9;
  const int bh = b * NH + h;
  const int q0 = qt * 64;
  const size_t kqbase = (size_t)bh * SLEN * 64;   // q,k: (b,h,s,d)
  const size_t vbase  = (size_t)bh * 64 * SLEN;   // vt: (b,h,d,s)

  bf16x8 qf[2];
  {
    const u16* qrow = q + kqbase + (size_t)(q0 + w * 16 + lm) * 64;
    qf[0] = *reinterpret_cast<const bf16x8*>(qrow + quad * 8);
    qf[1] = *reinterpret_cast<const bf16x8*>(qrow + 32 + quad * 8);
  }

  floatx4 o[4];
#pragma unroll
  for (int nt = 0; nt < 4; ++nt) o[nt] = (floatx4){0.f, 0.f, 0.f, 0.f};
  float lsum = 0.f;
  const int iq = q0 + w * 16 + lm;

  const int c_first = (q0 >= WIN) ? ((q0 - WIN) >> 6) : 0;
  const int c_last = q0 >> 6;

  const int sr = tid >> 3;                            // staging row 0..31
  const int scz = ((tid & 7) ^ (sr & 7)) * 8;         // inverse-swizzled chunk
  const u32 ksbase = (u32)(size_t)(__attribute__((address_space(3))) u16*)&Ks[0][0];
  const u32 vsbase = (u32)(size_t)(__attribute__((address_space(3))) u16*)&Vs[0][0];
  const u32 psbase = (u32)(size_t)(__attribute__((address_space(3))) u16*)&Ps[0][0][0];
  const int rxa8 = lm & 7;
  const u32 rowoff = (u32)lm * 128 + (u32)((quad ^ rxa8) * 16);
  const u32 paddr = psbase + (u32)(w * 16 + lm) * 144 + (u32)quad * 16;

  auto stage = [&](int c, int buf) {
    const u16* kg = k + kqbase + (size_t)(c << 6) * 64;
    const u16* vg = vt + vbase + (c << 6);
    u16* Kd = &Ks[buf][0]; u16* Vd = &Vs[buf][0];
    gl2lds16(kg + sr * 64 + scz, Kd + tid * 8);
    gl2lds16(kg + (sr + 32) * 64 + scz, Kd + 2048 + tid * 8);
    gl2lds16(vg + (size_t)sr * SLEN + scz, Vd + tid * 8);
    gl2lds16(vg + (size_t)(sr + 32) * SLEN + scz, Vd + 2048 + tid * 8);
  };

  stage(c_first, 0);
  int cur = 0;
  for (int c = c_first; c <= c_last; ++c) {
    const int c0 = c << 6;
    __syncthreads();
    if (c < c_last) stage(c + 1, cur ^ 1);

    // ---- QK^T: K frags via swizzled asm ds_read (conflict-free) ----
    const u32 kof = ksbase + (u32)(cur << 13) + rowoff;
    const u32 kof4 = kof ^ 64u;
    bf16x8 k00 = ldsr128<0>(kof),     k01 = ldsr128<2048>(kof),
           k02 = ldsr128<4096>(kof),  k03 = ldsr128<6144>(kof);
    bf16x8 k10 = ldsr128<0>(kof4),    k11 = ldsr128<2048>(kof4),
           k12 = ldsr128<4096>(kof4), k13 = ldsr128<6144>(kof4);
    SCHEDB;
    WAIT_LGKM0;
    SCHEDB;
    floatx4 st[4];
    const floatx4 z4 = (floatx4){0.f, 0.f, 0.f, 0.f};
    __builtin_amdgcn_s_setprio(1);
    st[0] = __builtin_amdgcn_mfma_f32_16x16x32_bf16(k00, qf[0], z4, 0, 0, 0);
    st[0] = __builtin_amdgcn_mfma_f32_16x16x32_bf16(k10, qf[1], st[0], 0, 0, 0);
    st[1] = __builtin_amdgcn_mfma_f32_16x16x32_bf16(k01, qf[0], z4, 0, 0, 0);
    st[1] = __builtin_amdgcn_mfma_f32_16x16x32_bf16(k11, qf[1], st[1], 0, 0, 0);
    st[2] = __builtin_amdgcn_mfma_f32_16x16x32_bf16(k02, qf[0], z4, 0, 0, 0);
    st[2] = __builtin_amdgcn_mfma_f32_16x16x32_bf16(k12, qf[1], st[2], 0, 0, 0);
    st[3] = __builtin_amdgcn_mfma_f32_16x16x32_bf16(k03, qf[0], z4, 0, 0, 0);
    st[3] = __builtin_amdgcn_mfma_f32_16x16x32_bf16(k13, qf[1], st[3], 0, 0, 0);
    __builtin_amdgcn_s_setprio(0);

    const bool need_mask = (c == c_first && q0 >= WIN) || (c == c_last);
    if (need_mask) {
#pragma unroll
      for (int mt = 0; mt < 4; ++mt)
#pragma unroll
        for (int r = 0; r < 4; ++r) {
          int j = c0 + mt * 16 + quad * 4 + r;
          bool valid = (j <= iq) && (j >= iq - WIN);
          if (!valid) st[mt][r] = -3.0e38f;
        }
    }
    float p[4][4], psum = 0.f;
#pragma unroll
    for (int mt = 0; mt < 4; ++mt)
#pragma unroll
      for (int r = 0; r < 4; ++r) {
        p[mt][r] = __expf(st[mt][r]);
        psum += p[mt][r];
      }
    psum += __shfl_xor(psum, 16);
    psum += __shfl_xor(psum, 32);
    lsum += psum;
#pragma unroll
    for (int mt = 0; mt < 4; ++mt) {
      union { u16 u[4]; u64 ll; } pk;
#pragma unroll
      for (int r = 0; r < 4; ++r) pk.u[r] = f2b(p[mt][r]);
      *reinterpret_cast<u64*>(&Ps[w][lm][mt * 16 + quad * 4]) = pk.ll;
    }
    __builtin_amdgcn_wave_barrier();
    __builtin_amdgcn_s_waitcnt(0xC07F);   // lgkmcnt(0): Ps writes visible
    __builtin_amdgcn_wave_barrier();

    // ---- PV: P frags + V frags via asm ds_read (V swizzled, conflict-free) ----
    bf16x8 pa0 = ldsr128<0>(paddr), pa1 = ldsr128<64>(paddr);
    const u32 vof = vsbase + (u32)(cur << 13) + rowoff;
    const u32 vof4 = vof ^ 64u;
    bf16x8 v00 = ldsr128<0>(vof),     v01 = ldsr128<2048>(vof),
           v02 = ldsr128<4096>(vof),  v03 = ldsr128<6144>(vof);
    bf16x8 v10 = ldsr128<0>(vof4),    v11 = ldsr128<2048>(vof4),
           v12 = ldsr128<4096>(vof4), v13 = ldsr128<6144>(vof4);
    SCHEDB;
    WAIT_LGKM0;
    SCHEDB;
    __builtin_amdgcn_s_setprio(1);
    o[0] = __builtin_amdgcn_mfma_f32_16x16x32_bf16(pa0, v00, o[0], 0, 0, 0);
    o[0] = __builtin_amdgcn_mfma_f32_16x16x32_bf16(pa1, v10, o[0], 0, 0, 0);
    o[1] = __builtin_amdgcn_mfma_f32_16x16x32_bf16(pa0, v01, o[1], 0, 0, 0);
    o[1] = __builtin_amdgcn_mfma_f32_16x16x32_bf16(pa1, v11, o[1], 0, 0, 0);
    o[2] = __builtin_amdgcn_mfma_f32_16x16x32_bf16(pa0, v02, o[2], 0, 0, 0);
    o[2] = __builtin_amdgcn_mfma_f32_16x16x32_bf16(pa1, v12, o[2], 0, 0, 0);
    o[3] = __builtin_amdgcn_mfma_f32_16x16x32_bf16(pa0, v03, o[3], 0, 0, 0);
    o[3] = __builtin_amdgcn_mfma_f32_16x16x32_bf16(pa1, v13, o[3], 0, 0, 0);
    __builtin_amdgcn_s_setprio(0);

    cur ^= 1;
  }
  float linv[4], g[4];
#pragma unroll
  for (int r = 0; r < 4; ++r) {
    linv[r] = 1.0f / __shfl(lsum, quad * 4 + r);
    g[r] = gate[bh * SLEN + q0 + w * 16 + quad * 4 + r];
  }
#pragma unroll
  for (int r = 0; r < 4; ++r) {
    int i = q0 + w * 16 + quad * 4 + r;
    u16* xrow = X + ((size_t)(b * SLEN + i)) * 1024 + h * 64;
#pragma unroll
    for (int nt = 0; nt < 4; ++nt)
      xrow[nt * 16 + lm] = f2b(o[nt][r] * linv[r] * g[r]);
  }
}

// ---------------- launch ----------------
extern "C" void kernel_launch(void* const* d_in, const int* in_sizes, int n_in,
                              void* d_out, int out_size, void* d_ws, size_t ws_size,
                              hipStream_t stream) {
  (void)in_sizes; (void)n_in; (void)out_size; (void)ws_size;
  const float* tokens = (const float*)d_in[0];
  const float* vres   = (const float*)d_in[1];
  const float* Wq     = (const float*)d_in[2];
  const float* Wkv    = (const float*)d_in[3];
  const float* Wout   = (const float*)d_in[4];
  const float* Wgate  = (const float*)d_in[5];
  const float* Wmix   = (const float*)d_in[6];
  float* out = (float*)d_out;

  char* p = (char*)d_ws;
  auto alloc = [&](size_t bytes) { char* r = p; p += (bytes + 255) & ~(size_t)255; return r; };
  u16*  tokA   = (u16*)alloc(8192ull * 1024 * 2);
  u16*  WqkvT  = (u16*)alloc(3072ull * 1024 * 2);
  u16*  WoutT  = (u16*)alloc(1024ull * 1024 * 2);
  u16*  Wmg    = (u16*)alloc(32ull * 1024 * 2);
  float2* rtab = (float2*)alloc(65536ull * 8);
  u16*  qws    = (u16*)alloc(8388608ull * 2);       // (b,h,s,d) post rotary+scale
  u16*  kws    = (u16*)alloc(8388608ull * 2);       // (b,h,s,d) post rotary
  u16*  vws    = (u16*)alloc(8388608ull * 2);       // (b,h,d,s) transposed, post mix
  u16*  Xws    = (u16*)alloc(8388608ull * 2);       // attn out (b,s,h*d), post gate
  float* mixws = (float*)alloc(131072ull * 4);
  float* gatews= (float*)alloc(131072ull * 4);

  prep_all<<<9600, 256, 0, stream>>>(tokens, Wq, Wkv, Wout, Wmix, Wgate,
      (u64*)tokA, WqkvT, WoutT, Wmg, rtab);
  mixgate_mfma<<<64, 256, 0, stream>>>(tokA, Wmg, mixws, gatews);
  gemm_pipe<1><<<384, 512, 0, stream>>>(tokA, WqkvT, nullptr,
      qws, kws, vws, vres, mixws, rtab, 3072);
  attn_mfma_kernel<<<2048, 256, 0, stream>>>(qws, kws, vws, gatews, Xws);
  gemm_pipe<0><<<128, 512, 0, stream>>>(Xws, WoutT, out,
      nullptr, nullptr, nullptr, nullptr, nullptr, nullptr, 1024);
}

// Round 6
// 265.903 us; speedup vs baseline: 1.1141x; 1.1141x over previous
//
#include <hip/hip_runtime.h>

#define NH 16
#define SLEN 2048
#define DMODEL 1024
#define DHEAD 64
#define WIN 512
#define NB 4

typedef unsigned short u16;
typedef unsigned int u32;
typedef unsigned long long u64;
typedef __attribute__((ext_vector_type(8))) __bf16 bf16x8;
typedef __attribute__((ext_vector_type(4))) float floatx4;

__device__ __forceinline__ float b2f(u32 bits16) {
  union { u32 i; float f; } x; x.i = bits16 << 16; return x.f;
}
__device__ __forceinline__ u16 f2b(float f) {
  union { float f; u32 i; } x; x.f = f;
  u32 r = x.i + 0x7fffu + ((x.i >> 16) & 1u);
  return (u16)(r >> 16);
}

// async global->LDS, 16B/lane; LDS dest must be wave-uniform base + lane*16
__device__ __forceinline__ void gl2lds16(const u16* g, u16* l) {
  __builtin_amdgcn_global_load_lds(
      (const __attribute__((address_space(1))) unsigned int*)g,
      (__attribute__((address_space(3))) unsigned int*)l, 16, 0, 0);
}

// inline-asm LDS read: invisible to compiler alias analysis; completion is
// managed by explicit counted lgkmcnt + sched_barrier(0) (rule #18).
template<int OFF>
__device__ __forceinline__ bf16x8 ldsr128(u32 addr) {
  bf16x8 r;
  if constexpr (OFF == 0)
    asm volatile("ds_read_b128 %0, %1" : "=v"(r) : "v"(addr));
  else
    asm volatile("ds_read_b128 %0, %1 offset:%2" : "=v"(r) : "v"(addr), "i"(OFF));
  return r;
}

#define WAIT_VM6   asm volatile("s_waitcnt vmcnt(6)" ::: "memory")
#define WAIT_VM0   asm volatile("s_waitcnt vmcnt(0)" ::: "memory")
#define WAIT_LGKM8 asm volatile("s_waitcnt lgkmcnt(8)" ::: "memory")
#define WAIT_LGKM0 asm volatile("s_waitcnt lgkmcnt(0)" ::: "memory")
#define SCHEDB     __builtin_amdgcn_sched_barrier(0)

// ---------------- fused prep: cvt + weight packs + rotary table ----------------
__global__ __launch_bounds__(256) void prep_all(
    const float* __restrict__ tokens, const float* __restrict__ Wq,
    const float* __restrict__ Wkv, const float* __restrict__ Wout,
    const float* __restrict__ Wmix, const float* __restrict__ Wgate,
    u64* __restrict__ tokA64, u16* __restrict__ WqkvT, u16* __restrict__ WoutT,
    u16* __restrict__ Wmg, float2* __restrict__ rtab) {
  __shared__ u16 T[64][72];
  const int blk = blockIdx.x, tid = threadIdx.x;
  if (blk < 8192) {
    int i = blk * 256 + tid;
    float4 f = reinterpret_cast<const float4*>(tokens)[i];
    union { u16 u[4]; u64 ll; } pk;
    pk.u[0] = f2b(f.x); pk.u[1] = f2b(f.y); pk.u[2] = f2b(f.z); pk.u[3] = f2b(f.w);
    tokA64[i] = pk.ll;
  } else if (blk < 9216) {
    const float* src; u16* dst; int ld, nb, n0, k0;
    if (blk < 8960) {
      int tile = blk - 8192;                      // 48 n-tiles x 16 k-tiles
      n0 = (tile % 48) * 64; k0 = (tile / 48) * 64;
      if (n0 < 1024) { src = Wq; ld = 1024; nb = n0; }
      else { src = Wkv; ld = 2048; nb = n0 - 1024; }
      dst = WqkvT;
    } else {
      int tile = blk - 8960;                      // 16 x 16
      n0 = (tile % 16) * 64; k0 = (tile / 16) * 64;
      src = Wout; ld = 1024; nb = n0; dst = WoutT;
    }
#pragma unroll
    for (int i = 0; i < 16; ++i) {
      int e = i * 256 + tid;
      int kr = e >> 6, nc = e & 63;
      T[kr][nc] = f2b(src[(size_t)(k0 + kr) * ld + nb + nc]);
    }
    __syncthreads();
#pragma unroll
    for (int i = 0; i < 16; ++i) {
      int e = i * 256 + tid;
      int nr = e >> 6, kc = e & 63;
      dst[(size_t)(n0 + nr) * 1024 + k0 + kc] = T[kc][nr];
    }
  } else if (blk < 9344) {
    int idx = (blk - 9216) * 256 + tid;           // 32768
    int n = idx >> 10, k = idx & 1023;
    float v = (n < 16) ? Wmix[k * 16 + n] : Wgate[k * 16 + (n - 16)];
    Wmg[idx] = f2b(v);
  } else {
    int idx = (blk - 9344) * 256 + tid;           // 65536
    int s = idx >> 5, t = idx & 31;
    float inv = __expf((float)t * -0.2878231366f);
    float ang = (float)s * inv;
    float sn, cs;
    __sincosf(ang, &sn, &cs);
    rtab[idx] = make_float2(cs, sn);
  }
}

// ---------------- mix / gate via MFMA (2 waves/block, 16-row strips, 256 blocks) ----
__global__ __launch_bounds__(128) void mixgate_mfma(const u16* __restrict__ A,
    const u16* __restrict__ Wmg, float* __restrict__ mixws, float* __restrict__ gatews) {
  const int lane = threadIdx.x & 63, w = threadIdx.x >> 6;
  const int lm = lane & 15, quad = lane >> 4;
  const int row0 = (blockIdx.x * 2 + w) * 16;

  floatx4 acc[2];
  acc[0] = (floatx4){0.f, 0.f, 0.f, 0.f};
  acc[1] = (floatx4){0.f, 0.f, 0.f, 0.f};

#pragma unroll 4
  for (int k0 = 0; k0 < 1024; k0 += 32) {
    bf16x8 af = *reinterpret_cast<const bf16x8*>(
        &A[(size_t)(row0 + lm) * 1024 + k0 + quad * 8]);
    bf16x8 bf[2];
#pragma unroll
    for (int nt = 0; nt < 2; ++nt)
      bf[nt] = *reinterpret_cast<const bf16x8*>(
          &Wmg[(size_t)(nt * 16 + lm) * 1024 + k0 + quad * 8]);
#pragma unroll
    for (int nt = 0; nt < 2; ++nt)
      acc[nt] = __builtin_amdgcn_mfma_f32_16x16x32_bf16(af, bf[nt], acc[nt], 0, 0, 0);
  }

#pragma unroll
  for (int r = 0; r < 4; ++r) {
    int grow = row0 + quad * 4 + r;
    int b = grow >> 11, s = grow & 2047;
#pragma unroll
    for (int nt = 0; nt < 2; ++nt) {
      int n = nt * 16 + lm;
      float sig = 1.0f / (1.0f + __expf(-acc[nt][r]));
      int h = n & 15;
      (n < 16 ? mixws : gatews)[(b * NH + h) * SLEN + s] = sig;
    }
  }
}

// ---------------- pipelined MFMA bf16 GEMM (round-4 proven best; reverted) ----
template<int MODE>
__global__ __launch_bounds__(512, 2) void gemm_pipe(
    const u16* __restrict__ A, const u16* __restrict__ Bt,
    float* __restrict__ C,
    u16* __restrict__ qws, u16* __restrict__ kws, u16* __restrict__ vws,
    const float* __restrict__ vres, const float* __restrict__ mixws,
    const float2* __restrict__ rtab, int N) {
  __shared__ u16 smem[73728];                     // 3 x (As 32KB + Bs 16KB)
  const int tid = threadIdx.x;
  const int nbx = N >> 7;
  const int wg = (blockIdx.x & 7) * (gridDim.x >> 3) + (blockIdx.x >> 3);
  const int bx = wg % nbx, by = wg / nbx;
  const int row0 = by * 256, col0 = bx * 128;
  const int w = tid >> 6, lane = tid & 63;
  const int wr = (w >> 1) * 64, wc = (w & 1) * 64;
  const int lm = lane & 15, quad = lane >> 4;
  const int NT = 16;                              // K = 1024, BK = 64
  const int sr = tid >> 3, sc = tid & 7;
  const int sl0 = (sr * 8 + sc) * 8;
  const u16* gA = A + (size_t)(row0 + sr) * 1024 + ((sc ^ (sr & 7)) << 3);
  const u16* gB = Bt + (size_t)(col0 + sr) * 1024 + ((sc ^ (sr & 7)) << 3);

  const u32 ldsbase = (u32)(size_t)(__attribute__((address_space(3))) u16*)smem;
  u32 arow[2], brow[2];
#pragma unroll
  for (int j = 0; j < 2; ++j) {
    u32 cslot = (u32)((j * 4 + quad) ^ (lm & 7));
    arow[j] = (u32)(wr + lm) * 128 + cslot * 16;
    brow[j] = (u32)(wc + lm) * 128 + cslot * 16;
  }

  floatx4 acc[4][4];
#pragma unroll
  for (int i = 0; i < 4; ++i)
#pragma unroll
    for (int j = 0; j < 4; ++j)
      acc[i][j] = (floatx4){0.f, 0.f, 0.f, 0.f};

  auto stage3 = [&](u16* Sa, u16* Sb, int ks, int half) {
    if (half == 0) {
      gl2lds16(gA + ks, Sa + sl0);
      gl2lds16(gA + 65536 + ks, Sa + 4096 + sl0);
      gl2lds16(gB + ks, Sb + sl0);
    } else {
      gl2lds16(gA + 131072 + ks, Sa + 8192 + sl0);
      gl2lds16(gA + 196608 + ks, Sa + 12288 + sl0);
      gl2lds16(gB + 65536 + ks, Sb + 4096 + sl0);
    }
  };

#pragma unroll
  for (int tt = 0; tt < 2; ++tt) {
    u16* Sa = smem + tt * 24576;
    u16* Sb = Sa + 16384;
    stage3(Sa, Sb, tt * 64, 0);
    stage3(Sa, Sb, tt * 64, 1);
  }

  int cur = 0;
  for (int t = 0; t < NT; ++t) {
    int sidx = cur + 2; if (sidx >= 3) sidx -= 3;
    u16* Sa = smem + sidx * 24576;
    u16* Sb = Sa + 16384;
    const int ks = (t + 2) << 6;
    const bool do_stage = t < NT - 2;
    const u32 abase = ldsbase + (u32)cur * 49152u;

    if (t < NT - 1) { WAIT_VM6; } else { WAIT_VM0; }
    __builtin_amdgcn_s_barrier();

    const u32 a0 = abase + arow[0], b0 = abase + 32768u + brow[0];
    const u32 a1 = abase + arow[1], b1 = abase + 32768u + brow[1];
    bf16x8 af0[4], bf0[4], af1[4], bf1[4];
    af0[0] = ldsr128<0>(a0);    af0[1] = ldsr128<2048>(a0);
    af0[2] = ldsr128<4096>(a0); af0[3] = ldsr128<6144>(a0);
    bf0[0] = ldsr128<0>(b0);    bf0[1] = ldsr128<2048>(b0);
    bf0[2] = ldsr128<4096>(b0); bf0[3] = ldsr128<6144>(b0);
    af1[0] = ldsr128<0>(a1);    af1[1] = ldsr128<2048>(a1);
    af1[2] = ldsr128<4096>(a1); af1[3] = ldsr128<6144>(a1);
    bf1[0] = ldsr128<0>(b1);    bf1[1] = ldsr128<2048>(b1);
    bf1[2] = ldsr128<4096>(b1); bf1[3] = ldsr128<6144>(b1);
    if (do_stage) { stage3(Sa, Sb, ks, 0); stage3(Sa, Sb, ks, 1); }
    SCHEDB;
    WAIT_LGKM8;
    SCHEDB;
    __builtin_amdgcn_s_setprio(1);
#pragma unroll
    for (int mt = 0; mt < 4; ++mt)
#pragma unroll
      for (int nt = 0; nt < 4; ++nt)
        acc[mt][nt] = __builtin_amdgcn_mfma_f32_16x16x32_bf16(
            af0[mt], bf0[nt], acc[mt][nt], 0, 0, 0);
    __builtin_amdgcn_s_setprio(0);
    WAIT_LGKM0;
    SCHEDB;
    __builtin_amdgcn_s_setprio(1);
#pragma unroll
    for (int mt = 0; mt < 4; ++mt)
#pragma unroll
      for (int nt = 0; nt < 4; ++nt)
        acc[mt][nt] = __builtin_amdgcn_mfma_f32_16x16x32_bf16(
            af1[mt], bf1[nt], acc[mt][nt], 0, 0, 0);
    __builtin_amdgcn_s_setprio(0);

    cur += 1; if (cur >= 3) cur -= 3;
  }

  if (MODE == 0) {
#pragma unroll
    for (int mt = 0; mt < 4; ++mt)
#pragma unroll
      for (int r = 0; r < 4; ++r) {
        int grow = row0 + wr + mt * 16 + quad * 4 + r;
#pragma unroll
        for (int nt = 0; nt < 4; ++nt)
          C[(size_t)grow * N + col0 + wc + nt * 16 + lm] = acc[mt][nt][r];
      }
  } else {
    const int seg = col0 >> 10;                   // 0=q, 1=k, 2=v
    if (seg < 2) {
      u16* dst = seg ? kws : qws;
      const float qs = seg ? 1.0f : 0.125f;       // D^-0.5 on q
      const int colb = (col0 & 1023) + wc;
#pragma unroll
      for (int mt = 0; mt < 4; ++mt)
#pragma unroll
        for (int r = 0; r < 4; ++r) {
          int sg = row0 + wr + mt * 16 + quad * 4 + r;
          int b = sg >> 11, s = sg & 2047;
#pragma unroll
          for (int nt = 0; nt < 4; ++nt) {
            int nn = colb + nt * 16 + lm;
            int h = nn >> 6, d = nn & 63;
            float val = acc[mt][nt][r] * qs;
            float2 cs = rtab[(s << 5) + (d >> 1)];
            float partner = __shfl_xor(val, 1);
            float o = (d & 1) ? fmaf(val, cs.x, partner * cs.y)
                              : fmaf(val, cs.x, -partner * cs.y);
            dst[((size_t)((b * NH + h) * SLEN + s)) * 64 + d] = f2b(o);
          }
        }
    } else {
      const int h0 = (col0 - 2048) >> 6;
      const int p = (w & 1);
      const int b = row0 >> 11, s0 = row0 & 2047;
      const int bh = b * NH + h0 + p;
      u16 (*Vt)[264] = reinterpret_cast<u16(*)[264]>(smem + p * 16896);
      __syncthreads();
#pragma unroll
      for (int mt = 0; mt < 4; ++mt)
#pragma unroll
        for (int nt = 0; nt < 4; ++nt) {
          const int d = nt * 16 + lm;
          const int sl = wr + mt * 16 + quad * 4;
          union { u16 u[4]; u64 ll; } pk;
#pragma unroll
          for (int r = 0; r < 4; ++r) {
            int s = s0 + sl + r;
            float val = acc[mt][nt][r];
            float mv = mixws[bh * SLEN + s];
            float o = val + (vres[((size_t)(bh * SLEN + s)) * 64 + d] - val) * mv;
            pk.u[r] = f2b(o);
          }
          *reinterpret_cast<u64*>(&Vt[d][sl]) = pk.ll;
        }
      __syncthreads();
#pragma unroll
      for (int it = 0; it < 8; ++it) {
        int idx = it * 512 + tid;
        int ph = idx >> 11, rem = idx & 2047;
        int d = rem >> 5, ch = rem & 31;
        const u16* src = smem + ph * 16896 + d * 264 + ch * 8;
        u16* dst = vws + ((size_t)((b * NH + h0 + ph) * 64 + d)) * SLEN + s0 + ch * 8;
        *reinterpret_cast<uint4*>(dst) = *reinterpret_cast<const uint4*>(src);
      }
    }
  }
}

// ---------------- MFMA flash attention: swizzled K/V LDS + double-buffer ----------
// Block swizzle (T1): all 32 q-tiles of one (b,h) head get block ids with the
// SAME residue mod 8 -> dispatched to one XCD -> the head's 512KB K/V is read
// once per XCD instead of 8x (L2-local re-reads across q-tiles).
// id = grp*256 + qt*8 + r, where bh = grp*8 + r. Bijective over [0,2048).
__global__ __launch_bounds__(256) void attn_mfma_kernel(
    const u16* __restrict__ q, const u16* __restrict__ k, const u16* __restrict__ vt,
    const float* __restrict__ gate, u16* __restrict__ X) {
  __shared__ __align__(16) u16 Ks[2][4096];   // [buf][j 64][8 swizzled 16B chunks]
  __shared__ __align__(16) u16 Vs[2][4096];   // [buf][d 64][8 swizzled 16B chunks]
  __shared__ __align__(16) u16 Ps[4][16][72]; // [wave][q-local][j 64 + pad]
  const int tid = threadIdx.x;
  const int w = tid >> 6, lane = tid & 63;
  const int lm = lane & 15, quad = lane >> 4;
  const int sid = blockIdx.x;
  const int qt = (sid >> 3) & 31;
  const int bh = ((sid >> 8) << 3) | (sid & 7);   // head-group pinned to one XCD
  const int h = bh & 15;
  const int b = bh >> 4;
  const int q0 = qt * 64;
  const size_t kqbase = (size_t)bh * SLEN * 64;   // q,k: (b,h,s,d)
  const size_t vbase  = (size_t)bh * 64 * SLEN;   // vt: (b,h,d,s)

  bf16x8 qf[2];
  {
    const u16* qrow = q + kqbase + (size_t)(q0 + w * 16 + lm) * 64;
    qf[0] = *reinterpret_cast<const bf16x8*>(qrow + quad * 8);
    qf[1] = *reinterpret_cast<const bf16x8*>(qrow + 32 + quad * 8);
  }

  floatx4 o[4];
#pragma unroll
  for (int nt = 0; nt < 4; ++nt) o[nt] = (floatx4){0.f, 0.f, 0.f, 0.f};
  float lsum = 0.f;
  const int iq = q0 + w * 16 + lm;

  const int c_first = (q0 >= WIN) ? ((q0 - WIN) >> 6) : 0;
  const int c_last = q0 >> 6;

  const int sr = tid >> 3;                            // staging row 0..31
  const int scz = ((tid & 7) ^ (sr & 7)) * 8;         // inverse-swizzled chunk
  const u32 ksbase = (u32)(size_t)(__attribute__((address_space(3))) u16*)&Ks[0][0];
  const u32 vsbase = (u32)(size_t)(__attribute__((address_space(3))) u16*)&Vs[0][0];
  const u32 psbase = (u32)(size_t)(__attribute__((address_space(3))) u16*)&Ps[0][0][0];
  const int rxa8 = lm & 7;
  const u32 rowoff = (u32)lm * 128 + (u32)((quad ^ rxa8) * 16);
  const u32 paddr = psbase + (u32)(w * 16 + lm) * 144 + (u32)quad * 16;

  auto stage = [&](int c, int buf) {
    const u16* kg = k + kqbase + (size_t)(c << 6) * 64;
    const u16* vg = vt + vbase + (c << 6);
    u16* Kd = &Ks[buf][0]; u16* Vd = &Vs[buf][0];
    gl2lds16(kg + sr * 64 + scz, Kd + tid * 8);
    gl2lds16(kg + (sr + 32) * 64 + scz, Kd + 2048 + tid * 8);
    gl2lds16(vg + (size_t)sr * SLEN + scz, Vd + tid * 8);
    gl2lds16(vg + (size_t)(sr + 32) * SLEN + scz, Vd + 2048 + tid * 8);
  };

  stage(c_first, 0);
  int cur = 0;
  for (int c = c_first; c <= c_last; ++c) {
    const int c0 = c << 6;
    __syncthreads();
    if (c < c_last) stage(c + 1, cur ^ 1);

    // ---- QK^T: K frags via swizzled asm ds_read (conflict-free) ----
    const u32 kof = ksbase + (u32)(cur << 13) + rowoff;
    const u32 kof4 = kof ^ 64u;
    bf16x8 k00 = ldsr128<0>(kof),     k01 = ldsr128<2048>(kof),
           k02 = ldsr128<4096>(kof),  k03 = ldsr128<6144>(kof);
    bf16x8 k10 = ldsr128<0>(kof4),    k11 = ldsr128<2048>(kof4),
           k12 = ldsr128<4096>(kof4), k13 = ldsr128<6144>(kof4);
    SCHEDB;
    WAIT_LGKM0;
    SCHEDB;
    floatx4 st[4];
    const floatx4 z4 = (floatx4){0.f, 0.f, 0.f, 0.f};
    __builtin_amdgcn_s_setprio(1);
    st[0] = __builtin_amdgcn_mfma_f32_16x16x32_bf16(k00, qf[0], z4, 0, 0, 0);
    st[0] = __builtin_amdgcn_mfma_f32_16x16x32_bf16(k10, qf[1], st[0], 0, 0, 0);
    st[1] = __builtin_amdgcn_mfma_f32_16x16x32_bf16(k01, qf[0], z4, 0, 0, 0);
    st[1] = __builtin_amdgcn_mfma_f32_16x16x32_bf16(k11, qf[1], st[1], 0, 0, 0);
    st[2] = __builtin_amdgcn_mfma_f32_16x16x32_bf16(k02, qf[0], z4, 0, 0, 0);
    st[2] = __builtin_amdgcn_mfma_f32_16x16x32_bf16(k12, qf[1], st[2], 0, 0, 0);
    st[3] = __builtin_amdgcn_mfma_f32_16x16x32_bf16(k03, qf[0], z4, 0, 0, 0);
    st[3] = __builtin_amdgcn_mfma_f32_16x16x32_bf16(k13, qf[1], st[3], 0, 0, 0);
    __builtin_amdgcn_s_setprio(0);

    const bool need_mask = (c == c_first && q0 >= WIN) || (c == c_last);
    if (need_mask) {
#pragma unroll
      for (int mt = 0; mt < 4; ++mt)
#pragma unroll
        for (int r = 0; r < 4; ++r) {
          int j = c0 + mt * 16 + quad * 4 + r;
          bool valid = (j <= iq) && (j >= iq - WIN);
          if (!valid) st[mt][r] = -3.0e38f;
        }
    }
    float p[4][4], psum = 0.f;
#pragma unroll
    for (int mt = 0; mt < 4; ++mt)
#pragma unroll
      for (int r = 0; r < 4; ++r) {
        p[mt][r] = __expf(st[mt][r]);
        psum += p[mt][r];
      }
    psum += __shfl_xor(psum, 16);
    psum += __shfl_xor(psum, 32);
    lsum += psum;
#pragma unroll
    for (int mt = 0; mt < 4; ++mt) {
      union { u16 u[4]; u64 ll; } pk;
#pragma unroll
      for (int r = 0; r < 4; ++r) pk.u[r] = f2b(p[mt][r]);
      *reinterpret_cast<u64*>(&Ps[w][lm][mt * 16 + quad * 4]) = pk.ll;
    }
    __builtin_amdgcn_wave_barrier();
    __builtin_amdgcn_s_waitcnt(0xC07F);   // lgkmcnt(0): Ps writes visible
    __builtin_amdgcn_wave_barrier();

    // ---- PV: P frags + V frags via asm ds_read (V swizzled, conflict-free) ----
    bf16x8 pa0 = ldsr128<0>(paddr), pa1 = ldsr128<64>(paddr);
    const u32 vof = vsbase + (u32)(cur << 13) + rowoff;
    const u32 vof4 = vof ^ 64u;
    bf16x8 v00 = ldsr128<0>(vof),     v01 = ldsr128<2048>(vof),
           v02 = ldsr128<4096>(vof),  v03 = ldsr128<6144>(vof);
    bf16x8 v10 = ldsr128<0>(vof4),    v11 = ldsr128<2048>(vof4),
           v12 = ldsr128<4096>(vof4), v13 = ldsr128<6144>(vof4);
    SCHEDB;
    WAIT_LGKM0;
    SCHEDB;
    __builtin_amdgcn_s_setprio(1);
    o[0] = __builtin_amdgcn_mfma_f32_16x16x32_bf16(pa0, v00, o[0], 0, 0, 0);
    o[0] = __builtin_amdgcn_mfma_f32_16x16x32_bf16(pa1, v10, o[0], 0, 0, 0);
    o[1] = __builtin_amdgcn_mfma_f32_16x16x32_bf16(pa0, v01, o[1], 0, 0, 0);
    o[1] = __builtin_amdgcn_mfma_f32_16x16x32_bf16(pa1, v11, o[1], 0, 0, 0);
    o[2] = __builtin_amdgcn_mfma_f32_16x16x32_bf16(pa0, v02, o[2], 0, 0, 0);
    o[2] = __builtin_amdgcn_mfma_f32_16x16x32_bf16(pa1, v12, o[2], 0, 0, 0);
    o[3] = __builtin_amdgcn_mfma_f32_16x16x32_bf16(pa0, v03, o[3], 0, 0, 0);
    o[3] = __builtin_amdgcn_mfma_f32_16x16x32_bf16(pa1, v13, o[3], 0, 0, 0);
    __builtin_amdgcn_s_setprio(0);

    cur ^= 1;
  }
  float linv[4], g[4];
#pragma unroll
  for (int r = 0; r < 4; ++r) {
    linv[r] = 1.0f / __shfl(lsum, quad * 4 + r);
    g[r] = gate[bh * SLEN + q0 + w * 16 + quad * 4 + r];
  }
#pragma unroll
  for (int r = 0; r < 4; ++r) {
    int i = q0 + w * 16 + quad * 4 + r;
    u16* xrow = X + ((size_t)(b * SLEN + i)) * 1024 + h * 64;
#pragma unroll
    for (int nt = 0; nt < 4; ++nt)
      xrow[nt * 16 + lm] = f2b(o[nt][r] * linv[r] * g[r]);
  }
}

// ---------------- launch ----------------
extern "C" void kernel_launch(void* const* d_in, const int* in_sizes, int n_in,
                              void* d_out, int out_size, void* d_ws, size_t ws_size,
                              hipStream_t stream) {
  (void)in_sizes; (void)n_in; (void)out_size; (void)ws_size;
  const float* tokens = (const float*)d_in[0];
  const float* vres   = (const float*)d_in[1];
  const float* Wq     = (const float*)d_in[2];
  const float* Wkv    = (const float*)d_in[3];
  const float* Wout   = (const float*)d_in[4];
  const float* Wgate  = (const float*)d_in[5];
  const float* Wmix   = (const float*)d_in[6];
  float* out = (float*)d_out;

  char* p = (char*)d_ws;
  auto alloc = [&](size_t bytes) { char* r = p; p += (bytes + 255) & ~(size_t)255; return r; };
  u16*  tokA   = (u16*)alloc(8192ull * 1024 * 2);
  u16*  WqkvT  = (u16*)alloc(3072ull * 1024 * 2);
  u16*  WoutT  = (u16*)alloc(1024ull * 1024 * 2);
  u16*  Wmg    = (u16*)alloc(32ull * 1024 * 2);
  float2* rtab = (float2*)alloc(65536ull * 8);
  u16*  qws    = (u16*)alloc(8388608ull * 2);       // (b,h,s,d) post rotary+scale
  u16*  kws    = (u16*)alloc(8388608ull * 2);       // (b,h,s,d) post rotary
  u16*  vws    = (u16*)alloc(8388608ull * 2);       // (b,h,d,s) transposed, post mix
  u16*  Xws    = (u16*)alloc(8388608ull * 2);       // attn out (b,s,h*d), post gate
  float* mixws = (float*)alloc(131072ull * 4);
  float* gatews= (float*)alloc(131072ull * 4);

  prep_all<<<9600, 256, 0, stream>>>(tokens, Wq, Wkv, Wout, Wmix, Wgate,
      (u64*)tokA, WqkvT, WoutT, Wmg, rtab);
  mixgate_mfma<<<256, 128, 0, stream>>>(tokA, Wmg, mixws, gatews);
  gemm_pipe<1><<<768, 512, 0, stream>>>(tokA, WqkvT, nullptr,
      qws, kws, vws, vres, mixws, rtab, 3072);
  attn_mfma_kernel<<<2048, 256, 0, stream>>>(qws, kws, vws, gatews, Xws);
  gemm_pipe<0><<<256, 512, 0, stream>>>(Xws, WoutT, out,
      nullptr, nullptr, nullptr, nullptr, nullptr, nullptr, 1024);
}

// Round 8
// 254.987 us; speedup vs baseline: 1.1618x; 1.0428x over previous
//
#include <hip/hip_runtime.h>

#define NH 16
#define SLEN 2048
#define DMODEL 1024
#define DHEAD 64
#define WIN 512
#define NB 4

typedef unsigned short u16;
typedef unsigned int u32;
typedef unsigned long long u64;
typedef __attribute__((ext_vector_type(8))) __bf16 bf16x8;
typedef __attribute__((ext_vector_type(4))) float floatx4;

__device__ __forceinline__ float b2f(u32 bits16) {
  union { u32 i; float f; } x; x.i = bits16 << 16; return x.f;
}
__device__ __forceinline__ u16 f2b(float f) {
  union { float f; u32 i; } x; x.f = f;
  u32 r = x.i + 0x7fffu + ((x.i >> 16) & 1u);
  return (u16)(r >> 16);
}

// async global->LDS, 16B/lane; LDS dest must be wave-uniform base + lane*16
__device__ __forceinline__ void gl2lds16(const u16* g, u16* l) {
  __builtin_amdgcn_global_load_lds(
      (const __attribute__((address_space(1))) unsigned int*)g,
      (__attribute__((address_space(3))) unsigned int*)l, 16, 0, 0);
}

// inline-asm LDS read: invisible to compiler alias analysis; completion is
// managed by explicit counted lgkmcnt + sched_barrier(0) (rule #18).
template<int OFF>
__device__ __forceinline__ bf16x8 ldsr128(u32 addr) {
  bf16x8 r;
  if constexpr (OFF == 0)
    asm volatile("ds_read_b128 %0, %1" : "=v"(r) : "v"(addr));
  else
    asm volatile("ds_read_b128 %0, %1 offset:%2" : "=v"(r) : "v"(addr), "i"(OFF));
  return r;
}

#define WAIT_VM8   asm volatile("s_waitcnt vmcnt(8)" ::: "memory")
#define WAIT_VM0   asm volatile("s_waitcnt vmcnt(0)" ::: "memory")
#define WAIT_LGKM8 asm volatile("s_waitcnt lgkmcnt(8)" ::: "memory")
#define WAIT_LGKM0 asm volatile("s_waitcnt lgkmcnt(0)" ::: "memory")
#define SCHEDB     __builtin_amdgcn_sched_barrier(0)

// ---------------- fused prep: cvt + weight packs + rotary table ----------------
__global__ __launch_bounds__(256) void prep_all(
    const float* __restrict__ tokens, const float* __restrict__ Wq,
    const float* __restrict__ Wkv, const float* __restrict__ Wout,
    const float* __restrict__ Wmix, const float* __restrict__ Wgate,
    u64* __restrict__ tokA64, u16* __restrict__ WqkvT, u16* __restrict__ WoutT,
    u16* __restrict__ Wmg, float2* __restrict__ rtab) {
  __shared__ u16 T[64][72];
  const int blk = blockIdx.x, tid = threadIdx.x;
  if (blk < 8192) {
    int i = blk * 256 + tid;
    float4 f = reinterpret_cast<const float4*>(tokens)[i];
    union { u16 u[4]; u64 ll; } pk;
    pk.u[0] = f2b(f.x); pk.u[1] = f2b(f.y); pk.u[2] = f2b(f.z); pk.u[3] = f2b(f.w);
    tokA64[i] = pk.ll;
  } else if (blk < 9216) {
    const float* src; u16* dst; int ld, nb, n0, k0;
    if (blk < 8960) {
      int tile = blk - 8192;                      // 48 n-tiles x 16 k-tiles
      n0 = (tile % 48) * 64; k0 = (tile / 48) * 64;
      if (n0 < 1024) { src = Wq; ld = 1024; nb = n0; }
      else { src = Wkv; ld = 2048; nb = n0 - 1024; }
      dst = WqkvT;
    } else {
      int tile = blk - 8960;                      // 16 x 16
      n0 = (tile % 16) * 64; k0 = (tile / 16) * 64;
      src = Wout; ld = 1024; nb = n0; dst = WoutT;
    }
#pragma unroll
    for (int i = 0; i < 16; ++i) {
      int e = i * 256 + tid;
      int kr = e >> 6, nc = e & 63;
      T[kr][nc] = f2b(src[(size_t)(k0 + kr) * ld + nb + nc]);
    }
    __syncthreads();
#pragma unroll
    for (int i = 0; i < 16; ++i) {
      int e = i * 256 + tid;
      int nr = e >> 6, kc = e & 63;
      dst[(size_t)(n0 + nr) * 1024 + k0 + kc] = T[kc][nr];
    }
  } else if (blk < 9344) {
    int idx = (blk - 9216) * 256 + tid;           // 32768
    int n = idx >> 10, k = idx & 1023;
    float v = (n < 16) ? Wmix[k * 16 + n] : Wgate[k * 16 + (n - 16)];
    Wmg[idx] = f2b(v);
  } else {
    int idx = (blk - 9344) * 256 + tid;           // 65536
    int s = idx >> 5, t = idx & 31;
    float inv = __expf((float)t * -0.2878231366f);
    float ang = (float)s * inv;
    float sn, cs;
    __sincosf(ang, &sn, &cs);
    rtab[idx] = make_float2(cs, sn);
  }
}

// ---------------- mix / gate via MFMA (2 waves/block, 16-row strips, 256 blocks) ----
__global__ __launch_bounds__(128) void mixgate_mfma(const u16* __restrict__ A,
    const u16* __restrict__ Wmg, float* __restrict__ mixws, float* __restrict__ gatews) {
  const int lane = threadIdx.x & 63, w = threadIdx.x >> 6;
  const int lm = lane & 15, quad = lane >> 4;
  const int row0 = (blockIdx.x * 2 + w) * 16;

  floatx4 acc[2];
  acc[0] = (floatx4){0.f, 0.f, 0.f, 0.f};
  acc[1] = (floatx4){0.f, 0.f, 0.f, 0.f};

#pragma unroll 4
  for (int k0 = 0; k0 < 1024; k0 += 32) {
    bf16x8 af = *reinterpret_cast<const bf16x8*>(
        &A[(size_t)(row0 + lm) * 1024 + k0 + quad * 8]);
    bf16x8 bf[2];
#pragma unroll
    for (int nt = 0; nt < 2; ++nt)
      bf[nt] = *reinterpret_cast<const bf16x8*>(
          &Wmg[(size_t)(nt * 16 + lm) * 1024 + k0 + quad * 8]);
#pragma unroll
    for (int nt = 0; nt < 2; ++nt)
      acc[nt] = __builtin_amdgcn_mfma_f32_16x16x32_bf16(af, bf[nt], acc[nt], 0, 0, 0);
  }

#pragma unroll
  for (int r = 0; r < 4; ++r) {
    int grow = row0 + quad * 4 + r;
    int b = grow >> 11, s = grow & 2047;
#pragma unroll
    for (int nt = 0; nt < 2; ++nt) {
      int n = nt * 16 + lm;
      float sig = 1.0f / (1.0f + __expf(-acc[nt][r]));
      int h = n & 15;
      (n < 16 ? mixws : gatews)[(b * NH + h) * SLEN + s] = sig;
    }
  }
}

// ---------------- m97-geometry MFMA bf16 GEMM: 128x128, 2 blocks/CU ----------------
// BM=BN=128, BK=64. 4 waves 2x2 (64x64/wave). 2 LDS buffers x 32KB = 64KB
// -> 2 blocks/CU: cross-block TLP covers the tile-top stall.
// Depth-1 prefetch, counted vmcnt(8). Two barriers per tile (2-buffer ledger):
//   B_top : all waves finished READING buf[cur^1] at t-1 (safe to stage into it)
//   stage8(cur^1, t+1); WAIT_VM8 (own tile-t loads done; t+1's 8 in flight)
//   B_mid : after every wave's vmcnt -> ALL waves' tile-t loads landed
//   16 asm ds_read -> lgkm8 -> 16 MFMA -> lgkm0 -> 16 MFMA.
// (r7 NaN root-cause: vmcnt was AFTER the only barrier, so cross-wave staging
//  completion was never certified. vmcnt-then-barrier is the invariant.)
// Swizzle: chunk (row,c)[16B] at slot c^(row&7) via pre-swizzled global source.
template<int MODE>
__global__ __launch_bounds__(256, 2) void gemm_pipe(
    const u16* __restrict__ A, const u16* __restrict__ Bt,
    float* __restrict__ C,
    u16* __restrict__ qws, u16* __restrict__ kws, u16* __restrict__ vws,
    const float* __restrict__ vres, const float* __restrict__ mixws,
    const float2* __restrict__ rtab, int N) {
  __shared__ u16 smem[32768];                     // 64KB: 2 x (A 16KB + B 16KB)
  const int tid = threadIdx.x;
  const int nbx = N >> 7;
  const int wg = (blockIdx.x & 7) * (gridDim.x >> 3) + (blockIdx.x >> 3);
  const int bx = wg % nbx, by = wg / nbx;
  const int row0 = by * 128, col0 = bx * 128;
  const int w = tid >> 6, lane = tid & 63;
  const int wr = (w >> 1) * 64, wc = (w & 1) * 64;
  const int lm = lane & 15, quad = lane >> 4;
  const int NT = 16;                              // K = 1024, BK = 64
  const int sr = tid >> 3, sc = tid & 7;          // staging: rows sr+{0,32,64,96}
  const int sl0 = (sr * 8 + sc) * 8;              // u16 offset in tile region
  const u16* gA = A + (size_t)(row0 + sr) * 1024 + ((sc ^ (sr & 7)) << 3);
  const u16* gB = Bt + (size_t)(col0 + sr) * 1024 + ((sc ^ (sr & 7)) << 3);

  const u32 ldsbase = (u32)(size_t)(__attribute__((address_space(3))) u16*)smem;
  u32 arow[2], brow[2];                           // byte offsets within buffer
#pragma unroll
  for (int j = 0; j < 2; ++j) {
    u32 cslot = (u32)((j * 4 + quad) ^ (lm & 7));
    arow[j] = (u32)(wr + lm) * 128 + cslot * 16;
    brow[j] = 16384u + (u32)(wc + lm) * 128 + cslot * 16;
  }

  floatx4 acc[4][4];
#pragma unroll
  for (int i = 0; i < 4; ++i)
#pragma unroll
    for (int j = 0; j < 4; ++j)
      acc[i][j] = (floatx4){0.f, 0.f, 0.f, 0.f};

  auto stage8 = [&](int buf, int t2) {            // full tile: 8 x 4KB loads
    const int ks = t2 << 6;
    u16* Sa = smem + buf * 16384;
    u16* Sb = Sa + 8192;
    gl2lds16(gA + ks, Sa + sl0);
    gl2lds16(gA + 32 * 1024 + ks, Sa + 2048 + sl0);
    gl2lds16(gA + 64 * 1024 + ks, Sa + 4096 + sl0);
    gl2lds16(gA + 96 * 1024 + ks, Sa + 6144 + sl0);
    gl2lds16(gB + ks, Sb + sl0);
    gl2lds16(gB + 32 * 1024 + ks, Sb + 2048 + sl0);
    gl2lds16(gB + 64 * 1024 + ks, Sb + 4096 + sl0);
    gl2lds16(gB + 96 * 1024 + ks, Sb + 6144 + sl0);
  };

  stage8(0, 0);                                   // prologue
  for (int t = 0; t < NT; ++t) {
    const int cur = t & 1;
    const u32 abase = ldsbase + (u32)cur * 32768u;

    __builtin_amdgcn_s_barrier();                 // B_top: buf[cur^1] readers done
    if (t + 1 < NT) { stage8(cur ^ 1, t + 1); WAIT_VM8; }
    else            { WAIT_VM0; }
    __builtin_amdgcn_s_barrier();                 // B_mid: ALL tile-t loads landed
    SCHEDB;

    const u32 a0 = abase + arow[0], b0 = abase + brow[0];
    const u32 a1 = abase + arow[1], b1 = abase + brow[1];
    bf16x8 af0[4], bf0[4], af1[4], bf1[4];
    af0[0] = ldsr128<0>(a0);    af0[1] = ldsr128<2048>(a0);
    af0[2] = ldsr128<4096>(a0); af0[3] = ldsr128<6144>(a0);
    bf0[0] = ldsr128<0>(b0);    bf0[1] = ldsr128<2048>(b0);
    bf0[2] = ldsr128<4096>(b0); bf0[3] = ldsr128<6144>(b0);
    af1[0] = ldsr128<0>(a1);    af1[1] = ldsr128<2048>(a1);
    af1[2] = ldsr128<4096>(a1); af1[3] = ldsr128<6144>(a1);
    bf1[0] = ldsr128<0>(b1);    bf1[1] = ldsr128<2048>(b1);
    bf1[2] = ldsr128<4096>(b1); bf1[3] = ldsr128<6144>(b1);
    SCHEDB;
    WAIT_LGKM8;
    SCHEDB;
    __builtin_amdgcn_s_setprio(1);
#pragma unroll
    for (int mt = 0; mt < 4; ++mt)
#pragma unroll
      for (int nt = 0; nt < 4; ++nt)
        acc[mt][nt] = __builtin_amdgcn_mfma_f32_16x16x32_bf16(
            af0[mt], bf0[nt], acc[mt][nt], 0, 0, 0);
    __builtin_amdgcn_s_setprio(0);
    WAIT_LGKM0;
    SCHEDB;
    __builtin_amdgcn_s_setprio(1);
#pragma unroll
    for (int mt = 0; mt < 4; ++mt)
#pragma unroll
      for (int nt = 0; nt < 4; ++nt)
        acc[mt][nt] = __builtin_amdgcn_mfma_f32_16x16x32_bf16(
            af1[mt], bf1[nt], acc[mt][nt], 0, 0, 0);
    __builtin_amdgcn_s_setprio(0);
  }

  if (MODE == 0) {
#pragma unroll
    for (int mt = 0; mt < 4; ++mt)
#pragma unroll
      for (int r = 0; r < 4; ++r) {
        int grow = row0 + wr + mt * 16 + quad * 4 + r;
#pragma unroll
        for (int nt = 0; nt < 4; ++nt)
          C[(size_t)grow * N + col0 + wc + nt * 16 + lm] = acc[mt][nt][r];
      }
  } else {
    const int seg = col0 >> 10;                   // 0=q, 1=k, 2=v (uniform/block)
    if (seg < 2) {
      u16* dst = seg ? kws : qws;
      const float qs = seg ? 1.0f : 0.125f;       // D^-0.5 on q
      const int colb = (col0 & 1023) + wc;
#pragma unroll
      for (int mt = 0; mt < 4; ++mt)
#pragma unroll
        for (int r = 0; r < 4; ++r) {
          int sg = row0 + wr + mt * 16 + quad * 4 + r;
          int b = sg >> 11, s = sg & 2047;
#pragma unroll
          for (int nt = 0; nt < 4; ++nt) {
            int nn = colb + nt * 16 + lm;
            int h = nn >> 6, d = nn & 63;
            float val = acc[mt][nt][r] * qs;
            float2 cs = rtab[(s << 5) + (d >> 1)];
            float partner = __shfl_xor(val, 1);
            float o = (d & 1) ? fmaf(val, cs.x, partner * cs.y)
                              : fmaf(val, cs.x, -partner * cs.y);
            dst[((size_t)((b * NH + h) * SLEN + s)) * 64 + d] = f2b(o);
          }
        }
    } else {
      // v: blend with residual by mix, transpose to (b,h,d,s) via LDS.
      // Block covers 2 heads; wave parity p=(w&1) selects head; waves {0,2}/{1,3}
      // cover rows via wr. Vt per head: [64 d][128 s + pad] stride 136 u16.
      const int h0 = (col0 - 2048) >> 6;
      const int p = w & 1;
      const int b = row0 >> 11, s0 = row0 & 2047;
      const int bh = b * NH + h0 + p;
      u16* VtW = smem + p * 8704;                 // per-head 64*136 u16
      __syncthreads();                            // main-loop smem retired
#pragma unroll
      for (int mt = 0; mt < 4; ++mt)
#pragma unroll
        for (int nt = 0; nt < 4; ++nt) {
          const int d = nt * 16 + lm;
          const int sl = wr + mt * 16 + quad * 4;
          union { u16 u[4]; u64 ll; } pk;
#pragma unroll
          for (int r = 0; r < 4; ++r) {
            int s = s0 + sl + r;
            float val = acc[mt][nt][r];
            float mv = mixws[bh * SLEN + s];
            float o = val + (vres[((size_t)(bh * SLEN + s)) * 64 + d] - val) * mv;
            pk.u[r] = f2b(o);
          }
          *reinterpret_cast<u64*>(&VtW[d * 136 + sl]) = pk.ll;
        }
      __syncthreads();
      // copy out: 2 heads x 64 d x 16 chunks(16B) = 2048 chunks / 256 thr
#pragma unroll
      for (int it = 0; it < 8; ++it) {
        int idx = it * 256 + tid;
        int ph = idx >> 10, rem = idx & 1023;
        int d = rem >> 4, ch = rem & 15;
        const u16* src = smem + ph * 8704 + d * 136 + ch * 8;
        u16* dstp = vws + ((size_t)((b * NH + h0 + ph) * 64 + d)) * SLEN + s0 + ch * 8;
        *reinterpret_cast<uint4*>(dstp) = *reinterpret_cast<const uint4*>(src);
      }
    }
  }
}

// ---------------- MFMA flash attention: swizzled K/V LDS + double-buffer ----------
// Block swizzle (T1): all 32 q-tiles of one (b,h) head get block ids with the
// SAME residue mod 8 -> one XCD owns each head's K/V (L2-local re-reads).
__global__ __launch_bounds__(256) void attn_mfma_kernel(
    const u16* __restrict__ q, const u16* __restrict__ k, const u16* __restrict__ vt,
    const float* __restrict__ gate, u16* __restrict__ X) {
  __shared__ __align__(16) u16 Ks[2][4096];   // [buf][j 64][8 swizzled 16B chunks]
  __shared__ __align__(16) u16 Vs[2][4096];   // [buf][d 64][8 swizzled 16B chunks]
  __shared__ __align__(16) u16 Ps[4][16][72]; // [wave][q-local][j 64 + pad]
  const int tid = threadIdx.x;
  const int w = tid >> 6, lane = tid & 63;
  const int lm = lane & 15, quad = lane >> 4;
  const int sid = blockIdx.x;
  const int qt = (sid >> 3) & 31;
  const int bh = ((sid >> 8) << 3) | (sid & 7);   // head-group pinned to one XCD
  const int h = bh & 15;
  const int b = bh >> 4;
  const int q0 = qt * 64;
  const size_t kqbase = (size_t)bh * SLEN * 64;   // q,k: (b,h,s,d)
  const size_t vbase  = (size_t)bh * 64 * SLEN;   // vt: (b,h,d,s)

  bf16x8 qf[2];
  {
    const u16* qrow = q + kqbase + (size_t)(q0 + w * 16 + lm) * 64;
    qf[0] = *reinterpret_cast<const bf16x8*>(qrow + quad * 8);
    qf[1] = *reinterpret_cast<const bf16x8*>(qrow + 32 + quad * 8);
  }

  floatx4 o[4];
#pragma unroll
  for (int nt = 0; nt < 4; ++nt) o[nt] = (floatx4){0.f, 0.f, 0.f, 0.f};
  float lsum = 0.f;
  const int iq = q0 + w * 16 + lm;

  const int c_first = (q0 >= WIN) ? ((q0 - WIN) >> 6) : 0;
  const int c_last = q0 >> 6;

  const int sr = tid >> 3;                            // staging row 0..31
  const int scz = ((tid & 7) ^ (sr & 7)) * 8;         // inverse-swizzled chunk
  const u32 ksbase = (u32)(size_t)(__attribute__((address_space(3))) u16*)&Ks[0][0];
  const u32 vsbase = (u32)(size_t)(__attribute__((address_space(3))) u16*)&Vs[0][0];
  const u32 psbase = (u32)(size_t)(__attribute__((address_space(3))) u16*)&Ps[0][0][0];
  const int rxa8 = lm & 7;
  const u32 rowoff = (u32)lm * 128 + (u32)((quad ^ rxa8) * 16);
  const u32 paddr = psbase + (u32)(w * 16 + lm) * 144 + (u32)quad * 16;

  auto stage = [&](int c, int buf) {
    const u16* kg = k + kqbase + (size_t)(c << 6) * 64;
    const u16* vg = vt + vbase + (c << 6);
    u16* Kd = &Ks[buf][0]; u16* Vd = &Vs[buf][0];
    gl2lds16(kg + sr * 64 + scz, Kd + tid * 8);
    gl2lds16(kg + (sr + 32) * 64 + scz, Kd + 2048 + tid * 8);
    gl2lds16(vg + (size_t)sr * SLEN + scz, Vd + tid * 8);
    gl2lds16(vg + (size_t)(sr + 32) * SLEN + scz, Vd + 2048 + tid * 8);
  };

  stage(c_first, 0);
  int cur = 0;
  for (int c = c_first; c <= c_last; ++c) {
    const int c0 = c << 6;
    __syncthreads();
    if (c < c_last) stage(c + 1, cur ^ 1);

    // ---- QK^T: K frags via swizzled asm ds_read (conflict-free) ----
    const u32 kof = ksbase + (u32)(cur << 13) + rowoff;
    const u32 kof4 = kof ^ 64u;
    bf16x8 k00 = ldsr128<0>(kof),     k01 = ldsr128<2048>(kof),
           k02 = ldsr128<4096>(kof),  k03 = ldsr128<6144>(kof);
    bf16x8 k10 = ldsr128<0>(kof4),    k11 = ldsr128<2048>(kof4),
           k12 = ldsr128<4096>(kof4), k13 = ldsr128<6144>(kof4);
    SCHEDB;
    WAIT_LGKM0;
    SCHEDB;
    floatx4 st[4];
    const floatx4 z4 = (floatx4){0.f, 0.f, 0.f, 0.f};
    __builtin_amdgcn_s_setprio(1);
    st[0] = __builtin_amdgcn_mfma_f32_16x16x32_bf16(k00, qf[0], z4, 0, 0, 0);
    st[0] = __builtin_amdgcn_mfma_f32_16x16x32_bf16(k10, qf[1], st[0], 0, 0, 0);
    st[1] = __builtin_amdgcn_mfma_f32_16x16x32_bf16(k01, qf[0], z4, 0, 0, 0);
    st[1] = __builtin_amdgcn_mfma_f32_16x16x32_bf16(k11, qf[1], st[1], 0, 0, 0);
    st[2] = __builtin_amdgcn_mfma_f32_16x16x32_bf16(k02, qf[0], z4, 0, 0, 0);
    st[2] = __builtin_amdgcn_mfma_f32_16x16x32_bf16(k12, qf[1], st[2], 0, 0, 0);
    st[3] = __builtin_amdgcn_mfma_f32_16x16x32_bf16(k03, qf[0], z4, 0, 0, 0);
    st[3] = __builtin_amdgcn_mfma_f32_16x16x32_bf16(k13, qf[1], st[3], 0, 0, 0);
    __builtin_amdgcn_s_setprio(0);

    const bool need_mask = (c == c_first && q0 >= WIN) || (c == c_last);
    if (need_mask) {
#pragma unroll
      for (int mt = 0; mt < 4; ++mt)
#pragma unroll
        for (int r = 0; r < 4; ++r) {
          int j = c0 + mt * 16 + quad * 4 + r;
          bool valid = (j <= iq) && (j >= iq - WIN);
          if (!valid) st[mt][r] = -3.0e38f;
        }
    }
    float p[4][4], psum = 0.f;
#pragma unroll
    for (int mt = 0; mt < 4; ++mt)
#pragma unroll
      for (int r = 0; r < 4; ++r) {
        p[mt][r] = __expf(st[mt][r]);
        psum += p[mt][r];
      }
    psum += __shfl_xor(psum, 16);
    psum += __shfl_xor(psum, 32);
    lsum += psum;
#pragma unroll
    for (int mt = 0; mt < 4; ++mt) {
      union { u16 u[4]; u64 ll; } pk;
#pragma unroll
      for (int r = 0; r < 4; ++r) pk.u[r] = f2b(p[mt][r]);
      *reinterpret_cast<u64*>(&Ps[w][lm][mt * 16 + quad * 4]) = pk.ll;
    }
    __builtin_amdgcn_wave_barrier();
    __builtin_amdgcn_s_waitcnt(0xC07F);   // lgkmcnt(0): Ps writes visible
    __builtin_amdgcn_wave_barrier();

    // ---- PV: P frags + V frags via asm ds_read (V swizzled, conflict-free) ----
    bf16x8 pa0 = ldsr128<0>(paddr), pa1 = ldsr128<64>(paddr);
    const u32 vof = vsbase + (u32)(cur << 13) + rowoff;
    const u32 vof4 = vof ^ 64u;
    bf16x8 v00 = ldsr128<0>(vof),     v01 = ldsr128<2048>(vof),
           v02 = ldsr128<4096>(vof),  v03 = ldsr128<6144>(vof);
    bf16x8 v10 = ldsr128<0>(vof4),    v11 = ldsr128<2048>(vof4),
           v12 = ldsr128<4096>(vof4), v13 = ldsr128<6144>(vof4);
    SCHEDB;
    WAIT_LGKM0;
    SCHEDB;
    __builtin_amdgcn_s_setprio(1);
    o[0] = __builtin_amdgcn_mfma_f32_16x16x32_bf16(pa0, v00, o[0], 0, 0, 0);
    o[0] = __builtin_amdgcn_mfma_f32_16x16x32_bf16(pa1, v10, o[0], 0, 0, 0);
    o[1] = __builtin_amdgcn_mfma_f32_16x16x32_bf16(pa0, v01, o[1], 0, 0, 0);
    o[1] = __builtin_amdgcn_mfma_f32_16x16x32_bf16(pa1, v11, o[1], 0, 0, 0);
    o[2] = __builtin_amdgcn_mfma_f32_16x16x32_bf16(pa0, v02, o[2], 0, 0, 0);
    o[2] = __builtin_amdgcn_mfma_f32_16x16x32_bf16(pa1, v12, o[2], 0, 0, 0);
    o[3] = __builtin_amdgcn_mfma_f32_16x16x32_bf16(pa0, v03, o[3], 0, 0, 0);
    o[3] = __builtin_amdgcn_mfma_f32_16x16x32_bf16(pa1, v13, o[3], 0, 0, 0);
    __builtin_amdgcn_s_setprio(0);

    cur ^= 1;
  }
  float linv[4], g[4];
#pragma unroll
  for (int r = 0; r < 4; ++r) {
    linv[r] = 1.0f / __shfl(lsum, quad * 4 + r);
    g[r] = gate[bh * SLEN + q0 + w * 16 + quad * 4 + r];
  }
#pragma unroll
  for (int r = 0; r < 4; ++r) {
    int i = q0 + w * 16 + quad * 4 + r;
    u16* xrow = X + ((size_t)(b * SLEN + i)) * 1024 + h * 64;
#pragma unroll
    for (int nt = 0; nt < 4; ++nt)
      xrow[nt * 16 + lm] = f2b(o[nt][r] * linv[r] * g[r]);
  }
}

// ---------------- launch ----------------
extern "C" void kernel_launch(void* const* d_in, const int* in_sizes, int n_in,
                              void* d_out, int out_size, void* d_ws, size_t ws_size,
                              hipStream_t stream) {
  (void)in_sizes; (void)n_in; (void)out_size; (void)ws_size;
  const float* tokens = (const float*)d_in[0];
  const float* vres   = (const float*)d_in[1];
  const float* Wq     = (const float*)d_in[2];
  const float* Wkv    = (const float*)d_in[3];
  const float* Wout   = (const float*)d_in[4];
  const float* Wgate  = (const float*)d_in[5];
  const float* Wmix   = (const float*)d_in[6];
  float* out = (float*)d_out;

  char* p = (char*)d_ws;
  auto alloc = [&](size_t bytes) { char* r = p; p += (bytes + 255) & ~(size_t)255; return r; };
  u16*  tokA   = (u16*)alloc(8192ull * 1024 * 2);
  u16*  WqkvT  = (u16*)alloc(3072ull * 1024 * 2);
  u16*  WoutT  = (u16*)alloc(1024ull * 1024 * 2);
  u16*  Wmg    = (u16*)alloc(32ull * 1024 * 2);
  float2* rtab = (float2*)alloc(65536ull * 8);
  u16*  qws    = (u16*)alloc(8388608ull * 2);       // (b,h,s,d) post rotary+scale
  u16*  kws    = (u16*)alloc(8388608ull * 2);       // (b,h,s,d) post rotary
  u16*  vws    = (u16*)alloc(8388608ull * 2);       // (b,h,d,s) transposed, post mix
  u16*  Xws    = (u16*)alloc(8388608ull * 2);       // attn out (b,s,h*d), post gate
  float* mixws = (float*)alloc(131072ull * 4);
  float* gatews= (float*)alloc(131072ull * 4);

  prep_all<<<9600, 256, 0, stream>>>(tokens, Wq, Wkv, Wout, Wmix, Wgate,
      (u64*)tokA, WqkvT, WoutT, Wmg, rtab);
  mixgate_mfma<<<256, 128, 0, stream>>>(tokA, Wmg, mixws, gatews);
  gemm_pipe<1><<<1536, 256, 0, stream>>>(tokA, WqkvT, nullptr,
      qws, kws, vws, vres, mixws, rtab, 3072);
  attn_mfma_kernel<<<2048, 256, 0, stream>>>(qws, kws, vws, gatews, Xws);
  gemm_pipe<0><<<512, 256, 0, stream>>>(Xws, WoutT, out,
      nullptr, nullptr, nullptr, nullptr, nullptr, nullptr, 1024);
}